// Round 8
// baseline (731.091 us; speedup 1.0000x reference)
//
#include <hip/hip_runtime.h>
#include <hip/hip_bf16.h>
#include <math.h>

#define H 12
#define S 384
#define V 64
#define D 768
#define PD_EPS 1e-6f

// element counts
#define TRANS_N (H*S*D)   // 3538944
#define P_N     (H*S*V)   // 294912
#define AO_N    (S*D)     // 294912

// workspace offsets (in floats)
#define WS_TRANS 0
#define WS_P     (WS_TRANS + TRANS_N)  // P until k_ao; then reused as res-copy by k_rowfix
#define WS_AO    (WS_P + P_N)          // 4 split-K slices
#define WS_MT    (WS_AO + 4*AO_N)
#define WS_COEF  (WS_MT + H*S)
#define WS_MH    (WS_COEF + S)
#define WS_BIAS  (WS_MH + S)
// total = WS_BIAS + D = 5019648 floats (~19.2 MB)

// output offsets (in floats): importance, tv_norm, tv_std, resultant
#define OUT_IMP   0
#define OUT_NORM  (S*S)
#define OUT_TVSTD (2*S*S)
#define OUT_RES   (2*S*S + (size_t)S*S*D)

__device__ __forceinline__ float block_sum256(float v, volatile float* tmp){
    #pragma unroll
    for (int m=1;m<64;m<<=1) v += __shfl_xor(v, m, 64);
    int w = threadIdx.x >> 6;
    __syncthreads();                  // protect tmp reuse across calls
    if ((threadIdx.x & 63)==0) tmp[w] = v;
    __syncthreads();
    return tmp[0]+tmp[1]+tmp[2]+tmp[3];
}

// DPP wave-64 sum: VALU pipe (v_mov_b32_dpp + v_add_f32), NOT the DS pipe like __shfl.
template<int CTRL, int RMASK>
__device__ __forceinline__ float dppadd(float x){
    int y = __builtin_amdgcn_update_dpp(0, __float_as_int(x), CTRL, RMASK, 0xf, true);
    return x + __int_as_float(y);
}
__device__ __forceinline__ float wave_sum64(float x){
    x = dppadd<0x111, 0xf>(x);   // row_shr:1
    x = dppadd<0x112, 0xf>(x);   // row_shr:2
    x = dppadd<0x114, 0xf>(x);   // row_shr:4
    x = dppadd<0x118, 0xf>(x);   // row_shr:8  -> lane15/31/47/63 hold row sums
    x = dppadd<0x142, 0xa>(x);   // row_bcast:15 into rows 1,3
    x = dppadd<0x143, 0xc>(x);   // row_bcast:31 into rows 2,3 -> lane63 = total
    return x;
}

// transformed[h,s,d] = sum_v value[h,s,v] * dense_w[d,h,v]
__global__ __launch_bounds__(256) void k_transformed(
    const float* __restrict__ value, const float* __restrict__ dense_w,
    float* __restrict__ ws)
{
    const int h  = blockIdx.x;              // 12
    const int s0 = blockIdx.y * 8;          // 48 tiles of 8 s
    const int d  = blockIdx.z * 256 + threadIdx.x; // 3 d-ranges
    __shared__ float vals[8*64];
    int t = threadIdx.x;
    vals[t]       = value[(size_t)(h*S + s0 + (t>>6))*V + (t&63)];
    int t2 = t + 256;
    vals[t2]      = value[(size_t)(h*S + s0 + (t2>>6))*V + (t2&63)];
    __syncthreads();
    const float4* wr4 = (const float4*)(dense_w + (size_t)(d*H + h)*V);
    float4 wr[16];
    #pragma unroll
    for (int i=0;i<16;i++) wr[i] = wr4[i];
    float* trans = ws + WS_TRANS;
    #pragma unroll
    for (int si=0; si<8; si++){
        float4 acc = make_float4(0.f,0.f,0.f,0.f);
        const float4* lv4 = (const float4*)(vals + si*64);
        #pragma unroll
        for (int i=0;i<16;i++){
            float4 lv = lv4[i];
            acc.x = fmaf(wr[i].x, lv.x, acc.x);
            acc.y = fmaf(wr[i].y, lv.y, acc.y);
            acc.z = fmaf(wr[i].z, lv.z, acc.z);
            acc.w = fmaf(wr[i].w, lv.w, acc.w);
        }
        trans[(size_t)(h*S + s0 + si)*D + d] = (acc.x+acc.y)+(acc.z+acc.w);
    }
}

// blocks 0..383: coef[s]=1/std(pre_ln[s]), mh[s]=mean(hidden[s])
// block 384: bias_term[d]
// blocks 385..: mt[h*S+s] = mean_d transformed
__global__ __launch_bounds__(256) void k_prep(
    const float* __restrict__ pre_ln, const float* __restrict__ hidden,
    const float* __restrict__ dense_bias, const float* __restrict__ ln_w,
    float* __restrict__ ws)
{
    __shared__ float tmp[4];
    int b = blockIdx.x;
    int t = threadIdx.x;
    if (b < S){
        float s1=0.f, s2=0.f, hs=0.f;
        #pragma unroll
        for (int j=0;j<3;j++){
            int d = t + j*256;
            float x = pre_ln[(size_t)b*D + d];
            s1 += x; s2 = fmaf(x,x,s2);
            hs += hidden[(size_t)b*D + d];
        }
        float sum1  = block_sum256(s1,tmp);
        float sumsq = block_sum256(s2,tmp);
        float hsum  = block_sum256(hs,tmp);
        if (t==0){
            float var = (sumsq - sum1*sum1/(float)D) / (float)(D-1);
            ws[WS_COEF + b] = 1.0f / sqrtf(var);
            ws[WS_MH + b]   = hsum / (float)D;
        }
    } else if (b == S){
        float s1=0.f;
        #pragma unroll
        for (int j=0;j<3;j++) s1 += dense_bias[t + j*256];
        float mean = block_sum256(s1,tmp) / (float)D;
        #pragma unroll
        for (int j=0;j<3;j++){
            int d = t + j*256;
            ws[WS_BIAS + d] = (dense_bias[d]-mean)*ln_w[d];
        }
    } else {
        int r = b - (S+1);   // 0..H*S-1
        float s1=0.f;
        #pragma unroll
        for (int j=0;j<3;j++) s1 += ws[WS_TRANS + (size_t)r*D + t + j*256];
        float sum = block_sum256(s1,tmp);
        if (t==0) ws[WS_MT + r] = sum / (float)D;
    }
}

// P[h,k,v] = sum_s attn[h,k,s] * value[h,s,v]  — one wave per (h,k), v=lane
__global__ __launch_bounds__(256) void k_P(
    const float* __restrict__ attn, const float* __restrict__ value,
    float* __restrict__ ws)
{
    int p = blockIdx.x*4 + (threadIdx.x>>6); // 0..4607
    int lane = threadIdx.x & 63;
    int h = p / S;
    int k = p - h*S;
    const float* ap = attn + (size_t)(h*S + k)*S;
    const float* vp = value + (size_t)h*S*V + lane;
    float a0=0.f,a1=0.f,a2=0.f,a3=0.f;
    for (int s=0;s<S;s+=4){
        a0 = fmaf(ap[s+0], vp[(size_t)(s+0)*V], a0);
        a1 = fmaf(ap[s+1], vp[(size_t)(s+1)*V], a1);
        a2 = fmaf(ap[s+2], vp[(size_t)(s+2)*V], a2);
        a3 = fmaf(ap[s+3], vp[(size_t)(s+3)*V], a3);
    }
    ws[WS_P + (size_t)p*V + lane] = (a0+a1)+(a2+a3);
}

// ao_part[z][k][d] = sum_{hv in z-slice} P2[k,hv] * dense_w[d*768+hv]
__global__ __launch_bounds__(256) void k_ao(const float* __restrict__ dense_w,
                                            float* __restrict__ ws)
{
    const int d0 = blockIdx.x * 64;   // 12
    const int k0 = blockIdx.y * 64;   // 6
    const int z  = blockIdx.z;        // 4 (hv slice of 192)
    __shared__ float As[64][17], Bs[64][17];
    const int tid = threadIdx.x;
    const int tx = tid & 15, ty = tid >> 4;
    float acc[4][4] = {};
    const float* Pw = ws + WS_P;
    for (int c=0;c<12;c++){
        int hv0 = z*192 + c*16;
        #pragma unroll
        for (int e = tid; e < 1024; e += 256){
            int row = e >> 4, col = e & 15;
            int hv = hv0 + col;
            int hh = hv >> 6, vv = hv & 63;
            As[row][col] = Pw[(size_t)(hh*S + k0 + row)*V + vv];
            Bs[row][col] = dense_w[(size_t)(d0 + row)*D + hv];
        }
        __syncthreads();
        #pragma unroll
        for (int kk=0;kk<16;kk++){
            float a[4],bv[4];
            #pragma unroll
            for (int i=0;i<4;i++) a[i]  = As[ty*4+i][kk];
            #pragma unroll
            for (int j=0;j<4;j++) bv[j] = Bs[tx*4+j][kk];
            #pragma unroll
            for (int i=0;i<4;i++)
                #pragma unroll
                for (int j=0;j<4;j++)
                    acc[i][j] = fmaf(a[i], bv[j], acc[i][j]);
        }
        __syncthreads();
    }
    float* ao = ws + WS_AO + (size_t)z*AO_N;
    #pragma unroll
    for (int i=0;i<4;i++)
        #pragma unroll
        for (int j=0;j<4;j++)
            ao[(size_t)(k0+ty*4+i)*D + d0 + tx*4 + j] = acc[i][j];
}

// resultant[k,d] = (w[d]*(sum_rwl - mean_d(sum_rwl)) + bias_term[d])*coef[k] + ln_b[d]
// also writes a copy of res into WS_P (dead after k_ao) so k_main can read it
// through a restrict'd ws pointer (out-aliasing blocked load hoisting in k_main).
__global__ __launch_bounds__(256) void k_rowfix(
    const float* __restrict__ hidden, const float* __restrict__ ln_w,
    const float* __restrict__ ln_b, float* __restrict__ ws, float* __restrict__ out)
{
    __shared__ float tmp[4];
    int k = blockIdx.x, t = threadIdx.x;
    float sr[3]; float tot = 0.f;
    #pragma unroll
    for (int j=0;j<3;j++){
        int d = t + j*256;
        float v = hidden[(size_t)k*D + d];
        #pragma unroll
        for (int z=0;z<4;z++) v += ws[WS_AO + (size_t)z*AO_N + (size_t)k*D + d];
        sr[j] = v; tot += v;
    }
    float msum = block_sum256(tot,tmp) / (float)D;
    float ck = ws[WS_COEF + k];
    float* res = out + OUT_RES;
    #pragma unroll
    for (int j=0;j<3;j++){
        int d = t + j*256;
        float ao = ln_w[d]*(sr[j]-msum);
        float val = (ao + ws[WS_BIAS+d])*ck + ln_b[d];
        res[(size_t)k*D + d] = val;
        ws[WS_P + (size_t)k*D + d] = val;   // res copy for k_main
    }
}

// v8 == v7's k_main (total 600us known). PROBE ROUND: k_main_probe re-runs the
// tv_std+norm core WITHOUT the res-load/iacc/imp path. T(probe)=total-600 splits
// k_main's 143us into {write+FMA core} vs {res/iacc path}.
#define KTILE 64
__global__ __launch_bounds__(256) void k_main(
    const float* __restrict__ attn, const float* __restrict__ hidden,
    const float* __restrict__ ln_w, const float* __restrict__ ws,
    float* __restrict__ out)
{
    const int k0 = blockIdx.x * KTILE;   // 6 k-tiles
    const int s  = blockIdx.y;           // 384
    const int t  = threadIdx.x;

    __shared__ float4 row4[KTILE][4];    // [kk] = {a'0..a'3}{a'4..a'7}{a'8..a'11}{m*ck,ck,-,-}
    __shared__ float2 red2[KTILE][4];    // per-kk per-wave (nacc,iacc)
    float* rowf = (float*)row4;

    // stage attn tile (scattered gather, once per block)
    for (int e = t; e < H*KTILE; e += 256){
        int h = e >> 6, kk = e & (KTILE-1);
        rowf[kk*16 + h] = attn[((size_t)(h*S + k0 + kk))*S + s];
    }

    const float* trans = ws + WS_TRANS;
    float T[H][3];
    #pragma unroll
    for (int h=0;h<H;h++)
        #pragma unroll
        for (int j=0;j<3;j++)
            T[h][j] = trans[(size_t)(h*S + s)*D + t + j*256];
    float wq[3];
    #pragma unroll
    for (int j=0;j<3;j++) wq[j] = ln_w[t + j*256];

    __syncthreads();
    if (t < KTILE){
        int k = k0 + t;
        float ck = ws[WS_COEF + k];
        float m = 0.f;
        #pragma unroll
        for (int h=0;h<H;h++) m = fmaf(rowf[t*16 + h], ws[WS_MT + h*S + s], m);
        if (k == s) m += ws[WS_MH + k];
        #pragma unroll
        for (int h=0;h<H;h++) rowf[t*16 + h] *= ck;   // fold ck into a'
        rowf[t*16 + 12] = m * ck;                     // m' = m*ck
        rowf[t*16 + 13] = ck;                         // raw ck for diag term
    }
    __syncthreads();

    const float* __restrict__ resw = ws + WS_P;   // res copy (not aliased with out)
    float* tvstd = out + OUT_TVSTD;
    const int lane = t & 63, wv = t >> 6;

    // pipelined state: A-row regs (current) + res regs (current)
    const float* rr = resw + (size_t)k0*D;
    float rp0 = rr[t], rp1 = rr[t+256], rp2 = rr[t+512];
    float4 C0 = row4[0][0], C1 = row4[0][1], C2 = row4[0][2], C3 = row4[0][3];

    for (int kk=0;kk<KTILE;kk++){
        const int k = k0 + kk;
        const float4 A0=C0, A1=C1, A2=C2, A3=C3;
        const float rc0=rp0, rc1=rp1, rc2=rp2;
        if (kk < KTILE-1){
            C0 = row4[kk+1][0]; C1 = row4[kk+1][1];
            C2 = row4[kk+1][2]; C3 = row4[kk+1][3];
            const float* rn = resw + (size_t)(k+1)*D;
            rp0 = rn[t]; rp1 = rn[t+256]; rp2 = rn[t+512];
        }
        const float mck = A3.x, ckv = A3.y;
        const bool diag = (k == s);
        float nacc=0.f, iacc=0.f;
        size_t rowbase = ((size_t)k*S + s)*D;
        const float rcur[3] = {rc0, rc1, rc2};
        #pragma unroll
        for (int j=0;j<3;j++){
            int d = t + j*256;
            float r;
            r = A0.x * T[0][j];
            r = fmaf(A0.y, T[1][j],  r);
            r = fmaf(A0.z, T[2][j],  r);
            r = fmaf(A0.w, T[3][j],  r);
            r = fmaf(A1.x, T[4][j],  r);
            r = fmaf(A1.y, T[5][j],  r);
            r = fmaf(A1.z, T[6][j],  r);
            r = fmaf(A1.w, T[7][j],  r);
            r = fmaf(A2.x, T[8][j],  r);
            r = fmaf(A2.y, T[9][j],  r);
            r = fmaf(A2.z, T[10][j], r);
            r = fmaf(A2.w, T[11][j], r);
            if (diag) r = fmaf(hidden[(size_t)k*D + d], ckv, r);
            float tvs = (r - mck) * wq[j];
            __builtin_nontemporal_store(tvs, &tvstd[rowbase + d]);
            nacc = fmaf(tvs,tvs,nacc);
            iacc += fabsf(tvs - rcur[j] + PD_EPS);
        }
        nacc = wave_sum64(nacc);
        iacc = wave_sum64(iacc);
        if (lane==63) red2[kk][wv] = make_float2(nacc, iacc);
    }
    __syncthreads();
    if (t < KTILE){
        int k = k0 + t;
        float2 q0=red2[t][0], q1=red2[t][1], q2=red2[t][2], q3=red2[t][3];
        float n  = q0.x+q1.x+q2.x+q3.x;
        float ii = q0.y+q1.y+q2.y+q3.y;
        __builtin_nontemporal_store(sqrtf(n), &out[OUT_NORM + (size_t)k*S + s]);
        __builtin_nontemporal_store(-ii,      &out[OUT_IMP  + (size_t)k*S + s]);
    }
}

// PROBE: identical core, NO res loads / iacc / imp store. Rewrites tv_std and
// norm with identical values (idempotent). T(probe) = total - 600.
__global__ __launch_bounds__(256) void k_main_probe(
    const float* __restrict__ attn, const float* __restrict__ hidden,
    const float* __restrict__ ln_w, const float* __restrict__ ws,
    float* __restrict__ out)
{
    const int k0 = blockIdx.x * KTILE;
    const int s  = blockIdx.y;
    const int t  = threadIdx.x;

    __shared__ float4 row4[KTILE][4];
    __shared__ float red1[KTILE][4];
    float* rowf = (float*)row4;

    for (int e = t; e < H*KTILE; e += 256){
        int h = e >> 6, kk = e & (KTILE-1);
        rowf[kk*16 + h] = attn[((size_t)(h*S + k0 + kk))*S + s];
    }

    const float* trans = ws + WS_TRANS;
    float T[H][3];
    #pragma unroll
    for (int h=0;h<H;h++)
        #pragma unroll
        for (int j=0;j<3;j++)
            T[h][j] = trans[(size_t)(h*S + s)*D + t + j*256];
    float wq[3];
    #pragma unroll
    for (int j=0;j<3;j++) wq[j] = ln_w[t + j*256];

    __syncthreads();
    if (t < KTILE){
        int k = k0 + t;
        float ck = ws[WS_COEF + k];
        float m = 0.f;
        #pragma unroll
        for (int h=0;h<H;h++) m = fmaf(rowf[t*16 + h], ws[WS_MT + h*S + s], m);
        if (k == s) m += ws[WS_MH + k];
        #pragma unroll
        for (int h=0;h<H;h++) rowf[t*16 + h] *= ck;
        rowf[t*16 + 12] = m * ck;
        rowf[t*16 + 13] = ck;
    }
    __syncthreads();

    float* tvstd = out + OUT_TVSTD;
    const int lane = t & 63, wv = t >> 6;
    float4 C0 = row4[0][0], C1 = row4[0][1], C2 = row4[0][2], C3 = row4[0][3];

    for (int kk=0;kk<KTILE;kk++){
        const int k = k0 + kk;
        const float4 A0=C0, A1=C1, A2=C2, A3=C3;
        if (kk < KTILE-1){
            C0 = row4[kk+1][0]; C1 = row4[kk+1][1];
            C2 = row4[kk+1][2]; C3 = row4[kk+1][3];
        }
        const float mck = A3.x, ckv = A3.y;
        const bool diag = (k == s);
        float nacc=0.f;
        size_t rowbase = ((size_t)k*S + s)*D;
        #pragma unroll
        for (int j=0;j<3;j++){
            int d = t + j*256;
            float r;
            r = A0.x * T[0][j];
            r = fmaf(A0.y, T[1][j],  r);
            r = fmaf(A0.z, T[2][j],  r);
            r = fmaf(A0.w, T[3][j],  r);
            r = fmaf(A1.x, T[4][j],  r);
            r = fmaf(A1.y, T[5][j],  r);
            r = fmaf(A1.z, T[6][j],  r);
            r = fmaf(A1.w, T[7][j],  r);
            r = fmaf(A2.x, T[8][j],  r);
            r = fmaf(A2.y, T[9][j],  r);
            r = fmaf(A2.z, T[10][j], r);
            r = fmaf(A2.w, T[11][j], r);
            if (diag) r = fmaf(hidden[(size_t)k*D + d], ckv, r);
            float tvs = (r - mck) * wq[j];
            __builtin_nontemporal_store(tvs, &tvstd[rowbase + d]);
            nacc = fmaf(tvs,tvs,nacc);
        }
        nacc = wave_sum64(nacc);
        if (lane==63) red1[kk][wv] = nacc;
    }
    __syncthreads();
    if (t < KTILE){
        int k = k0 + t;
        float n = red1[t][0]+red1[t][1]+red1[t][2]+red1[t][3];
        __builtin_nontemporal_store(sqrtf(n), &out[OUT_NORM + (size_t)k*S + s]);
    }
}

extern "C" void kernel_launch(void* const* d_in, const int* in_sizes, int n_in,
                              void* d_out, int out_size, void* d_ws, size_t ws_size,
                              hipStream_t stream)
{
    const float* value   = (const float*)d_in[0];
    const float* attn    = (const float*)d_in[1];
    const float* hidden  = (const float*)d_in[2];
    const float* pre_ln  = (const float*)d_in[3];
    const float* dense_w = (const float*)d_in[4];
    const float* dense_b = (const float*)d_in[5];
    const float* ln_w    = (const float*)d_in[6];
    const float* ln_b    = (const float*)d_in[7];
    float* out = (float*)d_out;
    float* ws  = (float*)d_ws;

    k_transformed<<<dim3(12,48,3),256,0,stream>>>(value, dense_w, ws);
    k_P<<<1152,256,0,stream>>>(attn, value, ws);
    k_prep<<<S+1+H*S,256,0,stream>>>(pre_ln, hidden, dense_b, ln_w, ws);
    k_ao<<<dim3(12,6,4),256,0,stream>>>(dense_w, ws);
    k_rowfix<<<S,256,0,stream>>>(hidden, ln_w, ln_b, ws, out);
    k_main<<<dim3(6,S),256,0,stream>>>(attn, hidden, ln_w, ws, out);
    // probe: core minus res/iacc/imp (idempotent rewrite of tv_std+norm)
    k_main_probe<<<dim3(6,S),256,0,stream>>>(attn, hidden, ln_w, ws, out);
}

// Round 9
// 584.193 us; speedup vs baseline: 1.2515x; 1.2515x over previous
//
#include <hip/hip_runtime.h>
#include <hip/hip_bf16.h>
#include <math.h>

#define H 12
#define S 384
#define V 64
#define D 768
#define PD_EPS 1e-6f

// element counts
#define TRANS_N (H*S*D)   // 3538944
#define P_N     (H*S*V)   // 294912
#define AO_N    (S*D)     // 294912

// workspace offsets (in floats)
#define WS_TRANS 0
#define WS_P     (WS_TRANS + TRANS_N)  // P until k_ao; then reused as res-copy by k_rowfix
#define WS_AO    (WS_P + P_N)          // 4 split-K slices
#define WS_MT    (WS_AO + 4*AO_N)
#define WS_COEF  (WS_MT + H*S)
#define WS_MH    (WS_COEF + S)
#define WS_BIAS  (WS_MH + S)
// total = WS_BIAS + D = 5019648 floats (~19.2 MB)

// output offsets (in floats): importance, tv_norm, tv_std, resultant
#define OUT_IMP   0
#define OUT_NORM  (S*S)
#define OUT_TVSTD (2*S*S)
#define OUT_RES   (2*S*S + (size_t)S*S*D)

__device__ __forceinline__ float block_sum256(float v, volatile float* tmp){
    #pragma unroll
    for (int m=1;m<64;m<<=1) v += __shfl_xor(v, m, 64);
    int w = threadIdx.x >> 6;
    __syncthreads();                  // protect tmp reuse across calls
    if ((threadIdx.x & 63)==0) tmp[w] = v;
    __syncthreads();
    return tmp[0]+tmp[1]+tmp[2]+tmp[3];
}

// DPP wave-64 sum: VALU pipe (v_mov_b32_dpp + v_add_f32), NOT the DS pipe like __shfl.
template<int CTRL, int RMASK>
__device__ __forceinline__ float dppadd(float x){
    int y = __builtin_amdgcn_update_dpp(0, __float_as_int(x), CTRL, RMASK, 0xf, true);
    return x + __int_as_float(y);
}
__device__ __forceinline__ float wave_sum64(float x){
    x = dppadd<0x111, 0xf>(x);   // row_shr:1
    x = dppadd<0x112, 0xf>(x);   // row_shr:2
    x = dppadd<0x114, 0xf>(x);   // row_shr:4
    x = dppadd<0x118, 0xf>(x);   // row_shr:8  -> lane15/31/47/63 hold row sums
    x = dppadd<0x142, 0xa>(x);   // row_bcast:15 into rows 1,3
    x = dppadd<0x143, 0xc>(x);   // row_bcast:31 into rows 2,3 -> lane63 = total
    return x;
}

// transformed[h,s,d] = sum_v value[h,s,v] * dense_w[d,h,v]
__global__ __launch_bounds__(256) void k_transformed(
    const float* __restrict__ value, const float* __restrict__ dense_w,
    float* __restrict__ ws)
{
    const int h  = blockIdx.x;              // 12
    const int s0 = blockIdx.y * 8;          // 48 tiles of 8 s
    const int d  = blockIdx.z * 256 + threadIdx.x; // 3 d-ranges
    __shared__ float vals[8*64];
    int t = threadIdx.x;
    vals[t]       = value[(size_t)(h*S + s0 + (t>>6))*V + (t&63)];
    int t2 = t + 256;
    vals[t2]      = value[(size_t)(h*S + s0 + (t2>>6))*V + (t2&63)];
    __syncthreads();
    const float4* wr4 = (const float4*)(dense_w + (size_t)(d*H + h)*V);
    float4 wr[16];
    #pragma unroll
    for (int i=0;i<16;i++) wr[i] = wr4[i];
    float* trans = ws + WS_TRANS;
    #pragma unroll
    for (int si=0; si<8; si++){
        float4 acc = make_float4(0.f,0.f,0.f,0.f);
        const float4* lv4 = (const float4*)(vals + si*64);
        #pragma unroll
        for (int i=0;i<16;i++){
            float4 lv = lv4[i];
            acc.x = fmaf(wr[i].x, lv.x, acc.x);
            acc.y = fmaf(wr[i].y, lv.y, acc.y);
            acc.z = fmaf(wr[i].z, lv.z, acc.z);
            acc.w = fmaf(wr[i].w, lv.w, acc.w);
        }
        trans[(size_t)(h*S + s0 + si)*D + d] = (acc.x+acc.y)+(acc.z+acc.w);
    }
}

// blocks 0..383: coef[s]=1/std(pre_ln[s]), mh[s]=mean(hidden[s])
// block 384: bias_term[d]
// blocks 385..: mt[h*S+s] = mean_d transformed
__global__ __launch_bounds__(256) void k_prep(
    const float* __restrict__ pre_ln, const float* __restrict__ hidden,
    const float* __restrict__ dense_bias, const float* __restrict__ ln_w,
    float* __restrict__ ws)
{
    __shared__ float tmp[4];
    int b = blockIdx.x;
    int t = threadIdx.x;
    if (b < S){
        float s1=0.f, s2=0.f, hs=0.f;
        #pragma unroll
        for (int j=0;j<3;j++){
            int d = t + j*256;
            float x = pre_ln[(size_t)b*D + d];
            s1 += x; s2 = fmaf(x,x,s2);
            hs += hidden[(size_t)b*D + d];
        }
        float sum1  = block_sum256(s1,tmp);
        float sumsq = block_sum256(s2,tmp);
        float hsum  = block_sum256(hs,tmp);
        if (t==0){
            float var = (sumsq - sum1*sum1/(float)D) / (float)(D-1);
            ws[WS_COEF + b] = 1.0f / sqrtf(var);
            ws[WS_MH + b]   = hsum / (float)D;
        }
    } else if (b == S){
        float s1=0.f;
        #pragma unroll
        for (int j=0;j<3;j++) s1 += dense_bias[t + j*256];
        float mean = block_sum256(s1,tmp) / (float)D;
        #pragma unroll
        for (int j=0;j<3;j++){
            int d = t + j*256;
            ws[WS_BIAS + d] = (dense_bias[d]-mean)*ln_w[d];
        }
    } else {
        int r = b - (S+1);   // 0..H*S-1
        float s1=0.f;
        #pragma unroll
        for (int j=0;j<3;j++) s1 += ws[WS_TRANS + (size_t)r*D + t + j*256];
        float sum = block_sum256(s1,tmp);
        if (t==0) ws[WS_MT + r] = sum / (float)D;
    }
}

// P[h,k,v] = sum_s attn[h,k,s] * value[h,s,v]  — one wave per (h,k), v=lane
__global__ __launch_bounds__(256) void k_P(
    const float* __restrict__ attn, const float* __restrict__ value,
    float* __restrict__ ws)
{
    int p = blockIdx.x*4 + (threadIdx.x>>6); // 0..4607
    int lane = threadIdx.x & 63;
    int h = p / S;
    int k = p - h*S;
    const float* ap = attn + (size_t)(h*S + k)*S;
    const float* vp = value + (size_t)h*S*V + lane;
    float a0=0.f,a1=0.f,a2=0.f,a3=0.f;
    for (int s=0;s<S;s+=4){
        a0 = fmaf(ap[s+0], vp[(size_t)(s+0)*V], a0);
        a1 = fmaf(ap[s+1], vp[(size_t)(s+1)*V], a1);
        a2 = fmaf(ap[s+2], vp[(size_t)(s+2)*V], a2);
        a3 = fmaf(ap[s+3], vp[(size_t)(s+3)*V], a3);
    }
    ws[WS_P + (size_t)p*V + lane] = (a0+a1)+(a2+a3);
}

// ao_part[z][k][d] = sum_{hv in z-slice} P2[k,hv] * dense_w[d*768+hv]
__global__ __launch_bounds__(256) void k_ao(const float* __restrict__ dense_w,
                                            float* __restrict__ ws)
{
    const int d0 = blockIdx.x * 64;   // 12
    const int k0 = blockIdx.y * 64;   // 6
    const int z  = blockIdx.z;        // 4 (hv slice of 192)
    __shared__ float As[64][17], Bs[64][17];
    const int tid = threadIdx.x;
    const int tx = tid & 15, ty = tid >> 4;
    float acc[4][4] = {};
    const float* Pw = ws + WS_P;
    for (int c=0;c<12;c++){
        int hv0 = z*192 + c*16;
        #pragma unroll
        for (int e = tid; e < 1024; e += 256){
            int row = e >> 4, col = e & 15;
            int hv = hv0 + col;
            int hh = hv >> 6, vv = hv & 63;
            As[row][col] = Pw[(size_t)(hh*S + k0 + row)*V + vv];
            Bs[row][col] = dense_w[(size_t)(d0 + row)*D + hv];
        }
        __syncthreads();
        #pragma unroll
        for (int kk=0;kk<16;kk++){
            float a[4],bv[4];
            #pragma unroll
            for (int i=0;i<4;i++) a[i]  = As[ty*4+i][kk];
            #pragma unroll
            for (int j=0;j<4;j++) bv[j] = Bs[tx*4+j][kk];
            #pragma unroll
            for (int i=0;i<4;i++)
                #pragma unroll
                for (int j=0;j<4;j++)
                    acc[i][j] = fmaf(a[i], bv[j], acc[i][j]);
        }
        __syncthreads();
    }
    float* ao = ws + WS_AO + (size_t)z*AO_N;
    #pragma unroll
    for (int i=0;i<4;i++)
        #pragma unroll
        for (int j=0;j<4;j++)
            ao[(size_t)(k0+ty*4+i)*D + d0 + tx*4 + j] = acc[i][j];
}

// resultant[k,d] = (w[d]*(sum_rwl - mean_d(sum_rwl)) + bias_term[d])*coef[k] + ln_b[d]
// also writes a copy of res into WS_P (dead after k_ao) so k_main can read it
// through a restrict'd ws pointer (out-aliasing blocked load hoisting in k_main).
__global__ __launch_bounds__(256) void k_rowfix(
    const float* __restrict__ hidden, const float* __restrict__ ln_w,
    const float* __restrict__ ln_b, float* __restrict__ ws, float* __restrict__ out)
{
    __shared__ float tmp[4];
    int k = blockIdx.x, t = threadIdx.x;
    float sr[3]; float tot = 0.f;
    #pragma unroll
    for (int j=0;j<3;j++){
        int d = t + j*256;
        float v = hidden[(size_t)k*D + d];
        #pragma unroll
        for (int z=0;z<4;z++) v += ws[WS_AO + (size_t)z*AO_N + (size_t)k*D + d];
        sr[j] = v; tot += v;
    }
    float msum = block_sum256(tot,tmp) / (float)D;
    float ck = ws[WS_COEF + k];
    float* res = out + OUT_RES;
    #pragma unroll
    for (int j=0;j<3;j++){
        int d = t + j*256;
        float ao = ln_w[d]*(sr[j]-msum);
        float val = (ao + ws[WS_BIAS+d])*ck + ln_b[d];
        res[(size_t)k*D + d] = val;
        ws[WS_P + (size_t)k*D + d] = val;   // res copy for k_main
    }
}

// v9: probe said core=127us vs 72us store floor (DS+store serializing; NT never
// A/B'd). Restructure the memory engines: 192 threads x 4 contiguous d each ->
// ONE plain global_store_dwordx4 per kk (fill-kernel recipe, NT dropped), float4
// T/res loads, 3 waves re-read the LDS row (was 4) as 3xb128+1xb64, wq folded
// into T (valid: wq is per-d scalar), res prefetch 1 ahead kept.
#define KTILE 64
__global__ __launch_bounds__(192) void k_main(
    const float* __restrict__ attn, const float* __restrict__ hidden,
    const float* __restrict__ ln_w, const float* __restrict__ ws,
    float* __restrict__ out)
{
    const int k0 = blockIdx.x * KTILE;   // 6 k-tiles
    const int s  = blockIdx.y;           // 384
    const int t  = threadIdx.x;          // 0..191
    const int d0 = t * 4;                // 4 contiguous d per thread

    __shared__ float4 row4[KTILE][4];    // [kk] = {a'0..3}{a'4..7}{a'8..11}{m*ck,ck,-,-}
    __shared__ float2 red2[KTILE][3];    // per-kk per-wave (nacc,iacc)
    float* rowf = (float*)row4;

    // stage attn tile (scattered gather, once per block): 768 elems / 192 thr
    #pragma unroll
    for (int e = t; e < H*KTILE; e += 192){
        int h = e >> 6, kk = e & (KTILE-1);
        rowf[kk*16 + h] = attn[((size_t)(h*S + k0 + kk))*S + s];
    }

    const float* trans = ws + WS_TRANS;
    const float4 wq4 = *(const float4*)(ln_w + d0);
    float4 T[H];                          // T' = trans * wq  (48 VGPR)
    #pragma unroll
    for (int h=0;h<H;h++){
        float4 v = *(const float4*)(trans + (size_t)(h*S + s)*D + d0);
        v.x *= wq4.x; v.y *= wq4.y; v.z *= wq4.z; v.w *= wq4.w;
        T[h] = v;
    }

    __syncthreads();
    if (t < KTILE){
        int k = k0 + t;
        float ck = ws[WS_COEF + k];
        float m = 0.f;
        #pragma unroll
        for (int h=0;h<H;h++) m = fmaf(rowf[t*16 + h], ws[WS_MT + h*S + s], m);
        if (k == s) m += ws[WS_MH + k];
        #pragma unroll
        for (int h=0;h<H;h++) rowf[t*16 + h] *= ck;   // fold ck into a'
        rowf[t*16 + 12] = m * ck;                     // m' = m*ck
        rowf[t*16 + 13] = ck;                         // raw ck for diag term
    }
    __syncthreads();

    const float* __restrict__ resw = ws + WS_P;   // res copy (not aliased with out)
    float* tvstd = out + OUT_TVSTD;
    const int lane = t & 63, wv = t >> 6;

    // pipelined state: A-row regs (current) + res float4 (current)
    float4 rp = *(const float4*)(resw + (size_t)k0*D + d0);
    float4 C0 = row4[0][0], C1 = row4[0][1], C2 = row4[0][2];
    float2 Cm = *(const float2*)(rowf + 13*0 + 12);  // {m*ck, ck} of row 0

    for (int kk=0;kk<KTILE;kk++){
        const int k = k0 + kk;
        const float4 A0=C0, A1=C1, A2=C2;
        const float4 rc = rp;
        const float mck = Cm.x, ckv = Cm.y;
        // issue next-kk loads EARLY (LDS + L2) so they complete under the FMAs
        if (kk < KTILE-1){
            C0 = row4[kk+1][0]; C1 = row4[kk+1][1]; C2 = row4[kk+1][2];
            Cm = *(const float2*)(rowf + (kk+1)*16 + 12);
            rp = *(const float4*)(resw + (size_t)(k+1)*D + d0);
        }
        const bool diag = (k == s);   // block-uniform branch
        float4 r;
        r.x = A0.x*T[0].x; r.y = A0.x*T[0].y; r.z = A0.x*T[0].z; r.w = A0.x*T[0].w;
        #define ACC(av) { r.x=fmaf(av,T[hh].x,r.x); r.y=fmaf(av,T[hh].y,r.y); \
                          r.z=fmaf(av,T[hh].z,r.z); r.w=fmaf(av,T[hh].w,r.w); }
        { constexpr int hh=1;  ACC(A0.y) } { constexpr int hh=2;  ACC(A0.z) }
        { constexpr int hh=3;  ACC(A0.w) } { constexpr int hh=4;  ACC(A1.x) }
        { constexpr int hh=5;  ACC(A1.y) } { constexpr int hh=6;  ACC(A1.z) }
        { constexpr int hh=7;  ACC(A1.w) } { constexpr int hh=8;  ACC(A2.x) }
        { constexpr int hh=9;  ACC(A2.y) } { constexpr int hh=10; ACC(A2.z) }
        { constexpr int hh=11; ACC(A2.w) }
        #undef ACC
        if (diag){
            const float4 hd = *(const float4*)(hidden + (size_t)k*D + d0);
            r.x = fmaf(hd.x*wq4.x, ckv, r.x);
            r.y = fmaf(hd.y*wq4.y, ckv, r.y);
            r.z = fmaf(hd.z*wq4.z, ckv, r.z);
            r.w = fmaf(hd.w*wq4.w, ckv, r.w);
        }
        float4 tv;
        tv.x = fmaf(-mck, wq4.x, r.x);
        tv.y = fmaf(-mck, wq4.y, r.y);
        tv.z = fmaf(-mck, wq4.z, r.z);
        tv.w = fmaf(-mck, wq4.w, r.w);
        // plain dwordx4 store (fill-kernel recipe; NT dropped)
        *(float4*)(tvstd + ((size_t)k*S + s)*D + d0) = tv;
        float nacc = tv.x*tv.x;
        nacc = fmaf(tv.y,tv.y,nacc); nacc = fmaf(tv.z,tv.z,nacc); nacc = fmaf(tv.w,tv.w,nacc);
        float iacc = fabsf(tv.x - rc.x + PD_EPS);
        iacc += fabsf(tv.y - rc.y + PD_EPS);
        iacc += fabsf(tv.z - rc.z + PD_EPS);
        iacc += fabsf(tv.w - rc.w + PD_EPS);
        nacc = wave_sum64(nacc);   // VALU-pipe DPP reduce, result in lane 63
        iacc = wave_sum64(iacc);
        if (lane==63) red2[kk][wv] = make_float2(nacc, iacc);
    }
    __syncthreads();
    if (t < KTILE){
        int k = k0 + t;
        float2 q0=red2[t][0], q1=red2[t][1], q2=red2[t][2];
        float n  = q0.x+q1.x+q2.x;
        float ii = q0.y+q1.y+q2.y;
        out[OUT_NORM + (size_t)k*S + s] = sqrtf(n);
        out[OUT_IMP  + (size_t)k*S + s] = -ii;
    }
}

extern "C" void kernel_launch(void* const* d_in, const int* in_sizes, int n_in,
                              void* d_out, int out_size, void* d_ws, size_t ws_size,
                              hipStream_t stream)
{
    const float* value   = (const float*)d_in[0];
    const float* attn    = (const float*)d_in[1];
    const float* hidden  = (const float*)d_in[2];
    const float* pre_ln  = (const float*)d_in[3];
    const float* dense_w = (const float*)d_in[4];
    const float* dense_b = (const float*)d_in[5];
    const float* ln_w    = (const float*)d_in[6];
    const float* ln_b    = (const float*)d_in[7];
    float* out = (float*)d_out;
    float* ws  = (float*)d_ws;

    k_transformed<<<dim3(12,48,3),256,0,stream>>>(value, dense_w, ws);
    k_P<<<1152,256,0,stream>>>(attn, value, ws);
    k_prep<<<S+1+H*S,256,0,stream>>>(pre_ln, hidden, dense_b, ln_w, ws);
    k_ao<<<dim3(12,6,4),256,0,stream>>>(dense_w, ws);
    k_rowfix<<<S,256,0,stream>>>(hidden, ln_w, ln_b, ws, out);
    k_main<<<dim3(6,S),192,0,stream>>>(attn, hidden, ln_w, ws, out);
}